// Round 1
// baseline (415.786 us; speedup 1.0000x reference)
//
#include <hip/hip_runtime.h>
#include <math.h>

#define PI_HALF 1.57079632679489662f

__device__ __forceinline__ float fast_tanh(float x) {
    float e = __expf(2.f * x);
    return 1.f - 2.f * __builtin_amdgcn_rcpf(e + 1.f);
}

// ---------------- 4-qubit state helpers (compile-time masks -> registers) ----
// wire w (0..3) maps to amplitude-index bit (3-w), i.e. mask = 8 >> w.

// state after per-wire RY layer on |0000>: amp = tensor product of (c,s) per wire.
// Bitwise-identical to sequential ry_g applications (same mult tree, commuted).
__device__ __forceinline__ void prod_init(float sr[16],
        float c0, float s0, float c1, float s1,
        float c2, float s2, float c3, float s3) {
    float p2[4];
    p2[0] = c0 * c1; p2[1] = c0 * s1; p2[2] = s0 * c1; p2[3] = s0 * s1;
    float p3[8];
#pragma unroll
    for (int j = 0; j < 4; ++j) { p3[2 * j] = p2[j] * c2; p3[2 * j + 1] = p2[j] * s2; }
#pragma unroll
    for (int j = 0; j < 8; ++j) { sr[2 * j] = p3[j] * c3; sr[2 * j + 1] = p3[j] * s3; }
}

template<int M>
__device__ __forceinline__ void had_r(float sr[16]) {
    const float r = 0.70710678118654752f;
#pragma unroll
    for (int i = 0; i < 16; ++i) {
        if (i & M) continue;
        const int j = i | M;
        float ar = sr[i], br = sr[j];
        sr[i] = (ar + br) * r;
        sr[j] = (ar - br) * r;
    }
}

template<int MC, int MT>
__device__ __forceinline__ void cry_r(float sr[16], float c, float s) {
#pragma unroll
    for (int i = 0; i < 16; ++i) {
        if (!(i & MC) || (i & MT)) continue;
        const int j = i | MT;
        float ar = sr[i], br = sr[j];
        sr[i] = c * ar - s * br;
        sr[j] = s * ar + c * br;
    }
}

template<int MC, int MT>
__device__ __forceinline__ void cnot_r(float sr[16]) {
#pragma unroll
    for (int i = 0; i < 16; ++i) {
        if (!(i & MC) || (i & MT)) continue;
        const int j = i | MT;
        float t = sr[i]; sr[i] = sr[j]; sr[j] = t;
    }
}

template<int MC, int MT>
__device__ __forceinline__ void cnot_g(float sr[16], float si[16]) {
#pragma unroll
    for (int i = 0; i < 16; ++i) {
        if (!(i & MC) || (i & MT)) continue;
        const int j = i | MT;
        float tr = sr[i], ti = si[i];
        sr[i] = sr[j]; si[i] = si[j];
        sr[j] = tr;    si[j] = ti;
    }
}

// full complex Rot gate from precomputed 8-float matrix
template<int M>
__device__ __forceinline__ void rot_pre(float sr[16], float si[16], const float* __restrict__ u) {
    const float u00r = u[0], u00i = u[1], u01r = u[2], u01i = u[3];
    const float u10r = u[4], u10i = u[5], u11r = u[6], u11i = u[7];
#pragma unroll
    for (int i = 0; i < 16; ++i) {
        if (i & M) continue;
        const int j = i | M;
        float ar = sr[i], ai = si[i], br = sr[j], bi = si[j];
        sr[i] = u00r * ar - u00i * ai + u01r * br - u01i * bi;
        si[i] = u00r * ai + u00i * ar + u01r * bi + u01i * br;
        sr[j] = u10r * ar - u10i * ai + u11r * br - u11i * bi;
        si[j] = u10r * ai + u10i * ar + u11r * bi + u11i * br;
    }
}

// first Rot applied to a purely-real state (si implicitly 0); bitwise-identical
// to rot_pre with ai=bi=0 (dropped terms are exact zeros).
template<int M>
__device__ __forceinline__ void rot_first(float sr[16], float si[16], const float* __restrict__ u) {
    const float u00r = u[0], u00i = u[1], u01r = u[2], u01i = u[3];
    const float u10r = u[4], u10i = u[5], u11r = u[6], u11i = u[7];
#pragma unroll
    for (int i = 0; i < 16; ++i) {
        if (i & M) continue;
        const int j = i | M;
        float ar = sr[i], br = sr[j];
        sr[i] = u00r * ar + u01r * br;
        si[i] = u00i * ar + u01i * br;
        sr[j] = u10r * ar + u11r * br;
        si[j] = u10i * ar + u11i * br;
    }
}

__device__ __forceinline__ void zexp_g(const float sr[16], const float si[16], float z[4]) {
    float p[16];
#pragma unroll
    for (int i = 0; i < 16; ++i) p[i] = sr[i] * sr[i] + si[i] * si[i];
    z[0] = z[1] = z[2] = z[3] = 0.f;
#pragma unroll
    for (int i = 0; i < 16; ++i) {
        z[0] += (i & 8) ? -p[i] : p[i];
        z[1] += (i & 4) ? -p[i] : p[i];
        z[2] += (i & 2) ? -p[i] : p[i];
        z[3] += (i & 1) ? -p[i] : p[i];
    }
}

// ---------------- kernels ---------------------------------------------------

// h = relu(x @ W_in^T + b_in) fused with k_fill + k_setup.
// Block roles: [0, eblocks) fill; eblocks: setup; (eblocks, ...] input GEMM (32 nodes/block).
__global__ void k_fsi(const int* __restrict__ ei, int* __restrict__ cur,
                      int* __restrict__ srcs, int* __restrict__ inv, int E, int EP,
                      const float* __restrict__ entp, const float* __restrict__ attqp,
                      const float* __restrict__ pparm,
                      const float* __restrict__ outW, const float* __restrict__ outb,
                      const float* __restrict__ poW, const float* __restrict__ pob,
                      float* __restrict__ rotbuf, float* __restrict__ M,
                      float* __restrict__ v,
                      const float* __restrict__ x, const float* __restrict__ W,
                      const float* __restrict__ b, float* __restrict__ h,
                      int N, int eblocks) {
    __shared__ float xs[32 * 64];
    const int bb = blockIdx.x;
    const int tid = threadIdx.x;  // 256
    if (bb < eblocks) {
        // -------- fill role (counting-sort scatter) --------
        int e = bb * 256 + tid;
        if (e < EP) {
            int s_, d_;
            if (e < E) { s_ = ei[e]; d_ = ei[E + e]; } else { s_ = d_ = e - E; }
            int pos = atomicAdd(&cur[d_], 1);
            srcs[pos] = s_;
            inv[e] = pos;
        }
        return;
    }
    if (bb == eblocks) {
        // -------- setup role: rot matrices + fused output matrix --------
        const int t = tid;
        if (t < 36) {
            const float* p;
            if (t < 16)      p = entp  + t * 3;
            else if (t < 24) p = attqp + (t - 16) * 3;
            else             p = pparm + (t - 24) * 3;
            float phi = p[0], theta = p[1], omega = p[2];
            float st, ct; sincosf(0.5f * theta, &st, &ct);
            float sp, cp; sincosf(0.5f * (phi + omega), &sp, &cp);
            float sm, cm; sincosf(0.5f * (phi - omega), &sm, &cm);
            float* u = rotbuf + t * 8;
            u[0] =  ct * cp;  u[1] = -ct * sp;
            u[2] = -st * cm;  u[3] = -st * sm;
            u[4] =  st * cm;  u[5] = -st * sm;
            u[6] =  ct * cp;  u[7] =  ct * sp;
        } else if (t >= 64 && t < 192) {
            int t2 = t - 64;
            int o = t2 >> 2, i = t2 & 3;
            float acc = 0.f;
            for (int j = 0; j < 128; ++j) acc += outW[o * 128 + j] * poW[j * 4 + i];
            M[t2] = acc;
        } else if (t >= 192 && t < 224) {
            int o = t - 192;
            float acc = outb[o];
            for (int j = 0; j < 128; ++j) acc += outW[o * 128 + j] * pob[j];
            v[o] = acc;
        }
        return;
    }
    // -------- input-GEMM role: 32 nodes per block, thread = (half, channel) --------
    const int base = (bb - eblocks - 1) * 32;
    for (int idx = tid; idx < 32 * 64; idx += 256) {
        int n = base + (idx >> 6);
        xs[idx] = (n < N) ? x[(size_t)n * 64 + (idx & 63)] : 0.f;
    }
    __syncthreads();
    const int ch = tid & 127;
    const int half = tid >> 7;
    float acc[16];
#pragma unroll
    for (int n = 0; n < 16; ++n) acc[n] = 0.f;
    const float4* wr4 = (const float4*)(W + ch * 64);
    for (int c4 = 0; c4 < 16; ++c4) {
        float4 w = wr4[c4];
#pragma unroll
        for (int n = 0; n < 16; ++n) {
            float4 hv = *(const float4*)&xs[(half * 16 + n) * 64 + c4 * 4];
            acc[n] += w.x * hv.x + w.y * hv.y + w.z * hv.z + w.w * hv.w;
        }
    }
    const float bbv = b[ch];
#pragma unroll
    for (int n = 0; n < 16; ++n) {
        int node = base + half * 16 + n;
        if (node < N) h[(size_t)node * 128 + ch] = fmaxf(acc[n] + bbv, 0.f);
    }
}

// entangle circuit (lanes 0-15) fused with per-node linear/x_comb/q/k kernel
__global__ void k_entlin(const float* __restrict__ h, const float* __restrict__ rotE2,
                         const float* __restrict__ linW, const float* __restrict__ linb,
                         const float* __restrict__ qpW, const float* __restrict__ qpb,
                         const float* __restrict__ aqW, const float* __restrict__ aqb,
                         const float* __restrict__ akW, const float* __restrict__ akb,
                         float* __restrict__ xcomb, float* __restrict__ qbuf,
                         float* __restrict__ kbuf, int N) {
    __shared__ float hs[16 * 128];
    __shared__ float xqs[16 * 4];
    const int base = blockIdx.x * 16;
    const int tid = threadIdx.x;  // 128
    for (int idx = tid; idx < 16 * 128; idx += 128) {
        int n = base + (idx >> 7);
        hs[idx] = (n < N) ? h[(size_t)n * 128 + (idx & 127)] : 0.f;
    }
    __syncthreads();
    if (tid < 16) {
        // entangle circuit for node base+tid; state real until first Rot.
        float4 hv = *(const float4*)&hs[tid * 128];
        float c0, s0, c1, s1, c2, s2, c3, s3;
        { float a = fast_tanh(hv.x) * (0.5f * PI_HALF); __sincosf(a, &s0, &c0); }
        { float a = fast_tanh(hv.y) * (0.5f * PI_HALF); __sincosf(a, &s1, &c1); }
        { float a = fast_tanh(hv.z) * (0.5f * PI_HALF); __sincosf(a, &s2, &c2); }
        { float a = fast_tanh(hv.w) * (0.5f * PI_HALF); __sincosf(a, &s3, &c3); }
        float sr[16], si[16];
        prod_init(sr, c0, s0, c1, s1, c2, s2, c3, s3);
        // sublayer 0: CNOTs real, first Rot real->complex
        cnot_r<8, 4>(sr); cnot_r<4, 2>(sr); cnot_r<2, 1>(sr);
        rot_first<8>(sr, si, rotE2);
        rot_pre<4>(sr, si, rotE2 + 8);
        rot_pre<2>(sr, si, rotE2 + 16);
        rot_pre<1>(sr, si, rotE2 + 24);
        cnot_g<8, 1>(sr, si);
        // sublayer 1: complex
        cnot_g<8, 4>(sr, si); cnot_g<4, 2>(sr, si); cnot_g<2, 1>(sr, si);
        const float* P = rotE2 + 32;
        rot_pre<8>(sr, si, P);
        rot_pre<4>(sr, si, P + 8);
        rot_pre<2>(sr, si, P + 16);
        rot_pre<1>(sr, si, P + 24);
        cnot_g<8, 1>(sr, si);
        float z[4]; zexp_g(sr, si, z);
        xqs[tid * 4 + 0] = z[0]; xqs[tid * 4 + 1] = z[1];
        xqs[tid * 4 + 2] = z[2]; xqs[tid * 4 + 3] = z[3];
    }
    __syncthreads();
    float acc[16];
#pragma unroll
    for (int n = 0; n < 16; ++n) acc[n] = 0.f;
    const float4* wr4 = (const float4*)(linW + tid * 128);
    for (int c4 = 0; c4 < 32; ++c4) {
        float4 w = wr4[c4];
#pragma unroll
        for (int n = 0; n < 16; ++n) {
            float4 hv = *(const float4*)&hs[n * 128 + c4 * 4];
            acc[n] += w.x * hv.x + w.y * hv.y + w.z * hv.z + w.w * hv.w;
        }
    }
    const float bb = linb[tid] + qpb[tid];
    const float qw0 = qpW[tid * 4 + 0], qw1 = qpW[tid * 4 + 1];
    const float qw2 = qpW[tid * 4 + 2], qw3 = qpW[tid * 4 + 3];
#pragma unroll
    for (int n = 0; n < 16; ++n) {
        int node = base + n;
        if (node < N) {
            xcomb[(size_t)node * 128 + tid] = acc[n] + bb
                + qw0 * xqs[n * 4 + 0] + qw1 * xqs[n * 4 + 1]
                + qw2 * xqs[n * 4 + 2] + qw3 * xqs[n * 4 + 3];
        }
    }
    const int nl = tid >> 3;
    const int which = tid & 7;
    const int qi = which & 3;
    const float4* Wp4 = (const float4*)(((which < 4) ? aqW : akW) + qi * 128);
    float dot = (which < 4) ? aqb[qi] : akb[qi];
    for (int c4 = 0; c4 < 32; ++c4) {
        float4 w = Wp4[c4];
        float4 hv = *(const float4*)&hs[nl * 128 + c4 * 4];
        dot += w.x * hv.x + w.y * hv.y + w.z * hv.z + w.w * hv.w;
    }
    int node = base + nl;
    if (node < N) {
        float halfang = fast_tanh(dot) * (0.5f * PI_HALF);
        float s, c; __sincosf(halfang, &s, &c);
        float* dst = ((which < 4) ? qbuf : kbuf) + (size_t)node * 8 + qi * 2;
        dst[0] = c; dst[1] = s;
    }
}

// attention circuit per edge. State is purely real through RY+H+CRY (all real
// gates); only the final Rot layer is complex. Score computed directly via
// popcount weights: mean_w z_w = sum_i p_i * (1 - popc(i)/2); 6 terms vanish.
__global__ void k_att(const float* __restrict__ qb, const float* __restrict__ kb,
                      const int* __restrict__ ei, const float* __restrict__ RA,
                      const int* __restrict__ inv, float* __restrict__ escore,
                      float* __restrict__ sumexp, int E, int EP) {
    __shared__ float red[4];
    int e = blockIdx.x * blockDim.x + threadIdx.x;
    float ex = 0.f;
    if (e < EP) {
        int s_, d_;
        if (e < E) { s_ = ei[e]; d_ = ei[E + e]; } else { s_ = d_ = e - E; }
        float4 qa = *(const float4*)&qb[(size_t)s_ * 8];
        float4 qc = *(const float4*)&qb[(size_t)s_ * 8 + 4];
        float4 ka = *(const float4*)&kb[(size_t)d_ * 8];
        float4 kc = *(const float4*)&kb[(size_t)d_ * 8 + 4];
        float sr[16], si[16];
        prod_init(sr, qa.x, qa.y, qa.z, qa.w, qc.x, qc.y, qc.z, qc.w);
        had_r<8>(sr); had_r<4>(sr); had_r<2>(sr); had_r<1>(sr);
        cry_r<8, 4>(sr, ka.x, ka.y);
        cry_r<4, 2>(sr, ka.z, ka.w);
        cry_r<2, 1>(sr, kc.x, kc.y);
        cry_r<1, 8>(sr, kc.z, kc.w);
        rot_first<8>(sr, si, RA);
        rot_pre<4>(sr, si, RA + 8);
        rot_pre<2>(sr, si, RA + 16);
        rot_pre<1>(sr, si, RA + 24);
        float p0  = sr[0]  * sr[0]  + si[0]  * si[0];
        float p1  = sr[1]  * sr[1]  + si[1]  * si[1];
        float p2  = sr[2]  * sr[2]  + si[2]  * si[2];
        float p4  = sr[4]  * sr[4]  + si[4]  * si[4];
        float p8  = sr[8]  * sr[8]  + si[8]  * si[8];
        float p7  = sr[7]  * sr[7]  + si[7]  * si[7];
        float p11 = sr[11] * sr[11] + si[11] * si[11];
        float p13 = sr[13] * sr[13] + si[13] * si[13];
        float p14 = sr[14] * sr[14] + si[14] * si[14];
        float p15 = sr[15] * sr[15] + si[15] * si[15];
        float sc = (p0 - p15) + 0.5f * ((p1 + p2 + p4 + p8) - (p7 + p11 + p13 + p14));
        ex = __expf(sc);
        escore[inv[e]] = ex;
    }
    float wsum = ex;
#pragma unroll
    for (int d = 32; d; d >>= 1) wsum += __shfl_xor(wsum, d, 64);
    if ((threadIdx.x & 63) == 0) red[threadIdx.x >> 6] = wsum;
    __syncthreads();
    if (threadIdx.x == 0) atomicAdd(sumexp, red[0] + red[1] + red[2] + red[3]);
}

// ---------------- dst binning (edge_index is layer-invariant: built once) ----

__global__ void k_hist(const int* __restrict__ ei, int* __restrict__ cnt, int E, int EP) {
    int e = blockIdx.x * blockDim.x + threadIdx.x;
    if (e >= EP) return;
    int d_ = (e < E) ? ei[E + e] : e - E;
    atomicAdd(&cnt[d_], 1);
}

__global__ void k_scan(const int* __restrict__ cnt, int* __restrict__ off,
                       int* __restrict__ cur, int N) {
    __shared__ int tot[1024];
    const int t = threadIdx.x;
    const int chunk = (N + 1023) >> 10;
    const int s0 = t * chunk;
    const int s1 = min(s0 + chunk, N);
    int sum = 0;
    for (int i = s0; i < s1; ++i) sum += cnt[i];
    tot[t] = sum;
    __syncthreads();
    for (int d = 1; d < 1024; d <<= 1) {
        int v = (t >= d) ? tot[t - d] : 0;
        __syncthreads();
        tot[t] += v;
        __syncthreads();
    }
    int run = (t == 0) ? 0 : tot[t - 1];
    for (int i = s0; i < s1; ++i) {
        off[i] = run; cur[i] = run;
        run += cnt[i];
    }
}

// one block per dst: h[dst,:] = relu( invS * sum_slot escore[slot]*xcomb[srcs[slot],:] )
__global__ void k_gather(const float* __restrict__ xcomb, const int* __restrict__ srcs,
                         const float* __restrict__ escore, const int* __restrict__ off,
                         const int* __restrict__ cnt, const float* __restrict__ sumexp,
                         float* __restrict__ h) {
    __shared__ int sS[128];
    __shared__ float wS[128];
    const int b = blockIdx.x;
    const int tid = threadIdx.x;  // 128
    const int start = off[b];
    const int num = cnt[b];
    float acc = 0.f;
    for (int base = 0; base < num; base += 128) {
        int m = min(128, num - base);
        if (tid < m) {
            sS[tid] = srcs[start + base + tid];
            wS[tid] = escore[start + base + tid];
        }
        __syncthreads();
        for (int i = 0; i < m; ++i)
            acc += wS[i] * xcomb[(size_t)sS[i] * 128 + tid];
        __syncthreads();
    }
    const float invS = __builtin_amdgcn_rcpf(sumexp[0]);
    h[(size_t)b * 128 + tid] = fmaxf(acc * invS, 0.f);
}

// fused tail: path_in projection (pq) + path circuit + epilogue out = M@z + v.
// 64 threads, 64 nodes per block; all lanes active in the circuit phase.
__global__ void k_tail(const float* __restrict__ h, const float* __restrict__ piW,
                       const float* __restrict__ pib, const float* __restrict__ RP,
                       const float* __restrict__ M, const float* __restrict__ v,
                       float* __restrict__ out, int N) {
    __shared__ float hs[64 * 132];
    __shared__ float pqS[64 * 8];
    __shared__ float zS[64 * 4];
    __shared__ float MS[128];
    __shared__ float vS[32];
    const int tid = threadIdx.x;  // 64
    const int base = blockIdx.x * 64;
    MS[tid] = M[tid]; MS[tid + 64] = M[tid + 64];
    if (tid < 32) vS[tid] = v[tid];
    for (int idx = tid; idx < 64 * 128; idx += 64) {
        int n = base + (idx >> 7);
        hs[(idx >> 7) * 132 + (idx & 127)] = (n < N) ? h[(size_t)n * 128 + (idx & 127)] : 0.f;
    }
    __syncthreads();
    // phase 1: 4 projection dots per thread (64 nodes x 4 outputs)
    for (int rep = 0; rep < 4; ++rep) {
        int vt = rep * 64 + tid;
        int nl = vt >> 2, i = vt & 3;
        float dot = pib[i];
        const float4* w4 = (const float4*)(piW + i * 128);
        for (int c4 = 0; c4 < 32; ++c4) {
            float4 w = w4[c4];
            float4 hv = *(const float4*)&hs[nl * 132 + c4 * 4];
            dot += w.x * hv.x + w.y * hv.y + w.z * hv.z + w.w * hv.w;
        }
        float halfang = fast_tanh(dot) * (0.5f * PI_HALF);
        float s, c; __sincosf(halfang, &s, &c);
        pqS[nl * 8 + i * 2]     = c;
        pqS[nl * 8 + i * 2 + 1] = s;
    }
    __syncthreads();
    // phase 2: path circuit, one node per thread. H then RY gives a product
    // state with per-wire vector (r*(c-s), r*(c+s)); real until first Rot.
    {
        const float r = 0.70710678118654752f;
        float c0 = pqS[tid * 8 + 0], s0 = pqS[tid * 8 + 1];
        float c1 = pqS[tid * 8 + 2], s1 = pqS[tid * 8 + 3];
        float c2 = pqS[tid * 8 + 4], s2 = pqS[tid * 8 + 5];
        float c3 = pqS[tid * 8 + 6], s3 = pqS[tid * 8 + 7];
        float u0 = r * (c0 - s0), w0 = r * (c0 + s0);
        float u1 = r * (c1 - s1), w1 = r * (c1 + s1);
        float u2 = r * (c2 - s2), w2 = r * (c2 + s2);
        float u3 = r * (c3 - s3), w3 = r * (c3 + s3);
        float sr[16], si[16];
        prod_init(sr, u0, w0, u1, w1, u2, w2, u3, w3);
        // layer 0
        rot_first<8>(sr, si, RP);
        rot_pre<4>(sr, si, RP + 8);
        rot_pre<2>(sr, si, RP + 16);
        rot_pre<1>(sr, si, RP + 24);
        cnot_g<8, 4>(sr, si); cnot_g<4, 2>(sr, si); cnot_g<2, 1>(sr, si);
        // layers 1,2
#pragma unroll
        for (int l = 1; l < 3; ++l) {
            const float* P = RP + l * 32;
            rot_pre<8>(sr, si, P);
            rot_pre<4>(sr, si, P + 8);
            rot_pre<2>(sr, si, P + 16);
            rot_pre<1>(sr, si, P + 24);
            cnot_g<8, 4>(sr, si); cnot_g<4, 2>(sr, si); cnot_g<2, 1>(sr, si);
        }
        float z[4]; zexp_g(sr, si, z);
        zS[tid * 4 + 0] = z[0]; zS[tid * 4 + 1] = z[1];
        zS[tid * 4 + 2] = z[2]; zS[tid * 4 + 3] = z[3];
    }
    __syncthreads();
    // epilogue: 64 nodes x 32 outputs, coalesced
#pragma unroll
    for (int k = 0; k < 32; ++k) {
        int flat = k * 64 + tid;
        int nl = flat >> 5;
        int o = flat & 31;
        int node = base + nl;
        if (node < N) {
            out[(size_t)node * 32 + o] = vS[o]
                + MS[o * 4 + 0] * zS[nl * 4 + 0] + MS[o * 4 + 1] * zS[nl * 4 + 1]
                + MS[o * 4 + 2] * zS[nl * 4 + 2] + MS[o * 4 + 3] * zS[nl * 4 + 3];
        }
    }
}

// ---------------- launch ----------------------------------------------------

extern "C" void kernel_launch(void* const* d_in, const int* in_sizes, int n_in,
                              void* d_out, int out_size, void* d_ws, size_t ws_size,
                              hipStream_t stream) {
    const float* x     = (const float*)d_in[0];
    const float* W_in  = (const float*)d_in[1];
    const float* b_in  = (const float*)d_in[2];
    const float* linW  = (const float*)d_in[3];
    const float* linb  = (const float*)d_in[4];
    const float* qpW   = (const float*)d_in[5];
    const float* qpb   = (const float*)d_in[6];
    const float* entp  = (const float*)d_in[7];
    const float* aqW   = (const float*)d_in[8];
    const float* aqb   = (const float*)d_in[9];
    const float* akW   = (const float*)d_in[10];
    const float* akb   = (const float*)d_in[11];
    const float* attqp = (const float*)d_in[12];
    const float* pparm = (const float*)d_in[13];
    const float* piW   = (const float*)d_in[14];
    const float* pib   = (const float*)d_in[15];
    const float* poW   = (const float*)d_in[16];
    const float* pob   = (const float*)d_in[17];
    const float* outW  = (const float*)d_in[18];
    const float* outb  = (const float*)d_in[19];
    const int*   ei    = (const int*)d_in[20];

    const int N  = in_sizes[0] / 64;   // 20000
    const int E  = in_sizes[20] / 2;   // 300000
    const int EP = E + N;              // self-loops appended

    float* ws     = (float*)d_ws;
    float* h      = ws;
    float* xcomb  = h      + (size_t)N * 128;
    float* qbuf   = xcomb  + (size_t)N * 128;
    float* kbuf   = qbuf   + (size_t)N * 8;
    float* escore = kbuf   + (size_t)N * 8;
    float* rotbuf = escore + EP;
    float* Mm     = rotbuf + 36 * 8;
    float* vv     = Mm + 128;
    int*   cnt    = (int*)(vv + 32);
    float* sumexp = (float*)(cnt + N);   // 2 slots (one per layer), zeroed with cnt
    int*   off    = (int*)(sumexp + 4);
    int*   cur    = off + N;
    int*   srcs   = cur + N;
    int*   inv    = srcs + EP;

    const float* rotE = rotbuf;          // 16 matrices
    const float* rotA = rotbuf + 128;    // 8 matrices
    const float* rotP = rotbuf + 192;    // 12 matrices

    const int nb16 = (N + 15) / 16;
    const int nb32 = (N + 31) / 32;
    const int ebl  = (EP + 255) / 256;

    hipMemsetAsync(cnt, 0, (size_t)(N + 4) * sizeof(int), stream);
    k_hist<<<ebl, 256, 0, stream>>>(ei, cnt, E, EP);
    k_scan<<<1, 1024, 0, stream>>>(cnt, off, cur, N);
    k_fsi<<<ebl + 1 + nb32, 256, 0, stream>>>(ei, cur, srcs, inv, E, EP,
                                              entp, attqp, pparm, outW, outb, poW, pob,
                                              rotbuf, Mm, vv, x, W_in, b_in, h, N, ebl);

    for (int l = 0; l < 2; ++l) {
        k_entlin<<<nb16, 128, 0, stream>>>(h, rotE + l * 64,
            linW + (size_t)l * 128 * 128, linb + l * 128,
            qpW + (size_t)l * 128 * 4, qpb + l * 128,
            aqW + (size_t)l * 4 * 128, aqb + l * 4,
            akW + (size_t)l * 4 * 128, akb + l * 4,
            xcomb, qbuf, kbuf, N);
        k_att<<<ebl, 256, 0, stream>>>(qbuf, kbuf, ei, rotA + l * 32, inv,
                                       escore, sumexp + l, E, EP);
        k_gather<<<N, 128, 0, stream>>>(xcomb, srcs, escore, off, cnt, sumexp + l, h);
    }

    k_tail<<<(N + 63) / 64, 64, 0, stream>>>(h, piW, pib, rotP, Mm, vv, (float*)d_out, N);
}

// Round 2
// 381.395 us; speedup vs baseline: 1.0902x; 1.0902x over previous
//
#include <hip/hip_runtime.h>
#include <math.h>

#define PI_HALF 1.57079632679489662f

__device__ __forceinline__ float fast_tanh(float x) {
    float e = __expf(2.f * x);
    return 1.f - 2.f * __builtin_amdgcn_rcpf(e + 1.f);
}

// ---------------- 4-qubit state helpers (compile-time masks -> registers) ----
// wire w (0..3) maps to amplitude-index bit (3-w), i.e. mask = 8 >> w.

// state after per-wire RY layer on |0000>: amp = tensor product of (c,s) per wire.
__device__ __forceinline__ void prod_init(float sr[16],
        float c0, float s0, float c1, float s1,
        float c2, float s2, float c3, float s3) {
    float p2[4];
    p2[0] = c0 * c1; p2[1] = c0 * s1; p2[2] = s0 * c1; p2[3] = s0 * s1;
    float p3[8];
#pragma unroll
    for (int j = 0; j < 4; ++j) { p3[2 * j] = p2[j] * c2; p3[2 * j + 1] = p2[j] * s2; }
#pragma unroll
    for (int j = 0; j < 8; ++j) { sr[2 * j] = p3[j] * c3; sr[2 * j + 1] = p3[j] * s3; }
}

template<int M>
__device__ __forceinline__ void had_r(float sr[16]) {
    const float r = 0.70710678118654752f;
#pragma unroll
    for (int i = 0; i < 16; ++i) {
        if (i & M) continue;
        const int j = i | M;
        float ar = sr[i], br = sr[j];
        sr[i] = (ar + br) * r;
        sr[j] = (ar - br) * r;
    }
}

template<int MC, int MT>
__device__ __forceinline__ void cry_r(float sr[16], float c, float s) {
#pragma unroll
    for (int i = 0; i < 16; ++i) {
        if (!(i & MC) || (i & MT)) continue;
        const int j = i | MT;
        float ar = sr[i], br = sr[j];
        sr[i] = c * ar - s * br;
        sr[j] = s * ar + c * br;
    }
}

template<int MC, int MT>
__device__ __forceinline__ void cnot_r(float sr[16]) {
#pragma unroll
    for (int i = 0; i < 16; ++i) {
        if (!(i & MC) || (i & MT)) continue;
        const int j = i | MT;
        float t = sr[i]; sr[i] = sr[j]; sr[j] = t;
    }
}

template<int MC, int MT>
__device__ __forceinline__ void cnot_g(float sr[16], float si[16]) {
#pragma unroll
    for (int i = 0; i < 16; ++i) {
        if (!(i & MC) || (i & MT)) continue;
        const int j = i | MT;
        float tr = sr[i], ti = si[i];
        sr[i] = sr[j]; si[i] = si[j];
        sr[j] = tr;    si[j] = ti;
    }
}

// full complex Rot gate from precomputed 8-float matrix
template<int M>
__device__ __forceinline__ void rot_pre(float sr[16], float si[16], const float* __restrict__ u) {
    const float u00r = u[0], u00i = u[1], u01r = u[2], u01i = u[3];
    const float u10r = u[4], u10i = u[5], u11r = u[6], u11i = u[7];
#pragma unroll
    for (int i = 0; i < 16; ++i) {
        if (i & M) continue;
        const int j = i | M;
        float ar = sr[i], ai = si[i], br = sr[j], bi = si[j];
        sr[i] = u00r * ar - u00i * ai + u01r * br - u01i * bi;
        si[i] = u00r * ai + u00i * ar + u01r * bi + u01i * br;
        sr[j] = u10r * ar - u10i * ai + u11r * br - u11i * bi;
        si[j] = u10r * ai + u10i * ar + u11r * bi + u11i * br;
    }
}

// first Rot applied to a purely-real state (si implicitly 0); bitwise-identical
// to rot_pre with ai=bi=0 (dropped terms are exact zeros).
template<int M>
__device__ __forceinline__ void rot_first(float sr[16], float si[16], const float* __restrict__ u) {
    const float u00r = u[0], u00i = u[1], u01r = u[2], u01i = u[3];
    const float u10r = u[4], u10i = u[5], u11r = u[6], u11i = u[7];
#pragma unroll
    for (int i = 0; i < 16; ++i) {
        if (i & M) continue;
        const int j = i | M;
        float ar = sr[i], br = sr[j];
        sr[i] = u00r * ar + u01r * br;
        si[i] = u00i * ar + u01i * br;
        sr[j] = u10r * ar + u11r * br;
        si[j] = u10i * ar + u11i * br;
    }
}

__device__ __forceinline__ void zexp_g(const float sr[16], const float si[16], float z[4]) {
    float p[16];
#pragma unroll
    for (int i = 0; i < 16; ++i) p[i] = sr[i] * sr[i] + si[i] * si[i];
    z[0] = z[1] = z[2] = z[3] = 0.f;
#pragma unroll
    for (int i = 0; i < 16; ++i) {
        z[0] += (i & 8) ? -p[i] : p[i];
        z[1] += (i & 4) ? -p[i] : p[i];
        z[2] += (i & 2) ? -p[i] : p[i];
        z[3] += (i & 1) ? -p[i] : p[i];
    }
}

// ---------------- kernels ---------------------------------------------------

// h = relu(x @ W_in^T + b_in) fused with k_fill + k_setup.
// Block roles: [0, eblocks) fill; eblocks: setup; (eblocks, ...] input GEMM (32 nodes/block).
__global__ void k_fsi(const int* __restrict__ ei, int* __restrict__ cur,
                      int* __restrict__ srcs, int* __restrict__ inv, int E, int EP,
                      const float* __restrict__ entp, const float* __restrict__ attqp,
                      const float* __restrict__ pparm,
                      const float* __restrict__ outW, const float* __restrict__ outb,
                      const float* __restrict__ poW, const float* __restrict__ pob,
                      float* __restrict__ rotbuf, float* __restrict__ M,
                      float* __restrict__ v,
                      const float* __restrict__ x, const float* __restrict__ W,
                      const float* __restrict__ b, float* __restrict__ h,
                      int N, int eblocks) {
    __shared__ float xs[32 * 64];
    const int bb = blockIdx.x;
    const int tid = threadIdx.x;  // 256
    if (bb < eblocks) {
        // -------- fill role (counting-sort scatter) --------
        int e = bb * 256 + tid;
        if (e < EP) {
            int s_, d_;
            if (e < E) { s_ = ei[e]; d_ = ei[E + e]; } else { s_ = d_ = e - E; }
            int pos = atomicAdd(&cur[d_], 1);
            srcs[pos] = s_;
            inv[e] = pos;
        }
        return;
    }
    if (bb == eblocks) {
        // -------- setup role: rot matrices + fused output matrix --------
        const int t = tid;
        if (t < 36) {
            const float* p;
            if (t < 16)      p = entp  + t * 3;
            else if (t < 24) p = attqp + (t - 16) * 3;
            else             p = pparm + (t - 24) * 3;
            float phi = p[0], theta = p[1], omega = p[2];
            float st, ct; sincosf(0.5f * theta, &st, &ct);
            float sp, cp; sincosf(0.5f * (phi + omega), &sp, &cp);
            float sm, cm; sincosf(0.5f * (phi - omega), &sm, &cm);
            float* u = rotbuf + t * 8;
            u[0] =  ct * cp;  u[1] = -ct * sp;
            u[2] = -st * cm;  u[3] = -st * sm;
            u[4] =  st * cm;  u[5] = -st * sm;
            u[6] =  ct * cp;  u[7] =  ct * sp;
        } else if (t >= 64 && t < 192) {
            int t2 = t - 64;
            int o = t2 >> 2, i = t2 & 3;
            float acc = 0.f;
            for (int j = 0; j < 128; ++j) acc += outW[o * 128 + j] * poW[j * 4 + i];
            M[t2] = acc;
        } else if (t >= 192 && t < 224) {
            int o = t - 192;
            float acc = outb[o];
            for (int j = 0; j < 128; ++j) acc += outW[o * 128 + j] * pob[j];
            v[o] = acc;
        }
        return;
    }
    // -------- input-GEMM role: 32 nodes per block, thread = (half, channel) --------
    const int base = (bb - eblocks - 1) * 32;
    for (int idx = tid; idx < 32 * 64; idx += 256) {
        int n = base + (idx >> 6);
        xs[idx] = (n < N) ? x[(size_t)n * 64 + (idx & 63)] : 0.f;
    }
    __syncthreads();
    const int ch = tid & 127;
    const int half = tid >> 7;
    float acc[16];
#pragma unroll
    for (int n = 0; n < 16; ++n) acc[n] = 0.f;
    const float4* wr4 = (const float4*)(W + ch * 64);
    for (int c4 = 0; c4 < 16; ++c4) {
        float4 w = wr4[c4];
#pragma unroll
        for (int n = 0; n < 16; ++n) {
            float4 hv = *(const float4*)&xs[(half * 16 + n) * 64 + c4 * 4];
            acc[n] += w.x * hv.x + w.y * hv.y + w.z * hv.z + w.w * hv.w;
        }
    }
    const float bbv = b[ch];
#pragma unroll
    for (int n = 0; n < 16; ++n) {
        int node = base + half * 16 + n;
        if (node < N) h[(size_t)node * 128 + ch] = fmaxf(acc[n] + bbv, 0.f);
    }
}

// entangle circuit (lanes 0-15) fused with per-node linear/x_comb/q/k kernel
__global__ void k_entlin(const float* __restrict__ h, const float* __restrict__ rotE2,
                         const float* __restrict__ linW, const float* __restrict__ linb,
                         const float* __restrict__ qpW, const float* __restrict__ qpb,
                         const float* __restrict__ aqW, const float* __restrict__ aqb,
                         const float* __restrict__ akW, const float* __restrict__ akb,
                         float* __restrict__ xcomb, float* __restrict__ qbuf,
                         float* __restrict__ kbuf, int N) {
    __shared__ float hs[16 * 128];
    __shared__ float xqs[16 * 4];
    const int base = blockIdx.x * 16;
    const int tid = threadIdx.x;  // 128
    for (int idx = tid; idx < 16 * 128; idx += 128) {
        int n = base + (idx >> 7);
        hs[idx] = (n < N) ? h[(size_t)n * 128 + (idx & 127)] : 0.f;
    }
    __syncthreads();
    if (tid < 16) {
        // entangle circuit for node base+tid; state real until first Rot.
        float4 hv = *(const float4*)&hs[tid * 128];
        float c0, s0, c1, s1, c2, s2, c3, s3;
        { float a = fast_tanh(hv.x) * (0.5f * PI_HALF); __sincosf(a, &s0, &c0); }
        { float a = fast_tanh(hv.y) * (0.5f * PI_HALF); __sincosf(a, &s1, &c1); }
        { float a = fast_tanh(hv.z) * (0.5f * PI_HALF); __sincosf(a, &s2, &c2); }
        { float a = fast_tanh(hv.w) * (0.5f * PI_HALF); __sincosf(a, &s3, &c3); }
        float sr[16], si[16];
        prod_init(sr, c0, s0, c1, s1, c2, s2, c3, s3);
        // sublayer 0: CNOTs real, first Rot real->complex
        cnot_r<8, 4>(sr); cnot_r<4, 2>(sr); cnot_r<2, 1>(sr);
        rot_first<8>(sr, si, rotE2);
        rot_pre<4>(sr, si, rotE2 + 8);
        rot_pre<2>(sr, si, rotE2 + 16);
        rot_pre<1>(sr, si, rotE2 + 24);
        cnot_g<8, 1>(sr, si);
        // sublayer 1: complex
        cnot_g<8, 4>(sr, si); cnot_g<4, 2>(sr, si); cnot_g<2, 1>(sr, si);
        const float* P = rotE2 + 32;
        rot_pre<8>(sr, si, P);
        rot_pre<4>(sr, si, P + 8);
        rot_pre<2>(sr, si, P + 16);
        rot_pre<1>(sr, si, P + 24);
        cnot_g<8, 1>(sr, si);
        float z[4]; zexp_g(sr, si, z);
        xqs[tid * 4 + 0] = z[0]; xqs[tid * 4 + 1] = z[1];
        xqs[tid * 4 + 2] = z[2]; xqs[tid * 4 + 3] = z[3];
    }
    __syncthreads();
    float acc[16];
#pragma unroll
    for (int n = 0; n < 16; ++n) acc[n] = 0.f;
    const float4* wr4 = (const float4*)(linW + tid * 128);
    for (int c4 = 0; c4 < 32; ++c4) {
        float4 w = wr4[c4];
#pragma unroll
        for (int n = 0; n < 16; ++n) {
            float4 hv = *(const float4*)&hs[n * 128 + c4 * 4];
            acc[n] += w.x * hv.x + w.y * hv.y + w.z * hv.z + w.w * hv.w;
        }
    }
    const float bb = linb[tid] + qpb[tid];
    const float qw0 = qpW[tid * 4 + 0], qw1 = qpW[tid * 4 + 1];
    const float qw2 = qpW[tid * 4 + 2], qw3 = qpW[tid * 4 + 3];
#pragma unroll
    for (int n = 0; n < 16; ++n) {
        int node = base + n;
        if (node < N) {
            xcomb[(size_t)node * 128 + tid] = acc[n] + bb
                + qw0 * xqs[n * 4 + 0] + qw1 * xqs[n * 4 + 1]
                + qw2 * xqs[n * 4 + 2] + qw3 * xqs[n * 4 + 3];
        }
    }
    const int nl = tid >> 3;
    const int which = tid & 7;
    const int qi = which & 3;
    const float4* Wp4 = (const float4*)(((which < 4) ? aqW : akW) + qi * 128);
    float dot = (which < 4) ? aqb[qi] : akb[qi];
    for (int c4 = 0; c4 < 32; ++c4) {
        float4 w = Wp4[c4];
        float4 hv = *(const float4*)&hs[nl * 128 + c4 * 4];
        dot += w.x * hv.x + w.y * hv.y + w.z * hv.z + w.w * hv.w;
    }
    int node = base + nl;
    if (node < N) {
        float halfang = fast_tanh(dot) * (0.5f * PI_HALF);
        float s, c; __sincosf(halfang, &s, &c);
        float* dst = ((which < 4) ? qbuf : kbuf) + (size_t)node * 8 + qi * 2;
        dst[0] = c; dst[1] = s;
    }
}

// attention circuit per edge. State is purely real through RY+H+CRY (all real
// gates); only the final Rot layer is complex. Score computed directly via
// popcount weights: mean_w z_w = sum_i p_i * (1 - popc(i)/2); 6 terms vanish.
__global__ void k_att(const float* __restrict__ qb, const float* __restrict__ kb,
                      const int* __restrict__ ei, const float* __restrict__ RA,
                      const int* __restrict__ inv, float* __restrict__ escore,
                      float* __restrict__ sumexp, int E, int EP) {
    __shared__ float red[4];
    int e = blockIdx.x * blockDim.x + threadIdx.x;
    float ex = 0.f;
    if (e < EP) {
        int s_, d_;
        if (e < E) { s_ = ei[e]; d_ = ei[E + e]; } else { s_ = d_ = e - E; }
        float4 qa = *(const float4*)&qb[(size_t)s_ * 8];
        float4 qc = *(const float4*)&qb[(size_t)s_ * 8 + 4];
        float4 ka = *(const float4*)&kb[(size_t)d_ * 8];
        float4 kc = *(const float4*)&kb[(size_t)d_ * 8 + 4];
        float sr[16], si[16];
        prod_init(sr, qa.x, qa.y, qa.z, qa.w, qc.x, qc.y, qc.z, qc.w);
        had_r<8>(sr); had_r<4>(sr); had_r<2>(sr); had_r<1>(sr);
        cry_r<8, 4>(sr, ka.x, ka.y);
        cry_r<4, 2>(sr, ka.z, ka.w);
        cry_r<2, 1>(sr, kc.x, kc.y);
        cry_r<1, 8>(sr, kc.z, kc.w);
        rot_first<8>(sr, si, RA);
        rot_pre<4>(sr, si, RA + 8);
        rot_pre<2>(sr, si, RA + 16);
        rot_pre<1>(sr, si, RA + 24);
        float p0  = sr[0]  * sr[0]  + si[0]  * si[0];
        float p1  = sr[1]  * sr[1]  + si[1]  * si[1];
        float p2  = sr[2]  * sr[2]  + si[2]  * si[2];
        float p4  = sr[4]  * sr[4]  + si[4]  * si[4];
        float p8  = sr[8]  * sr[8]  + si[8]  * si[8];
        float p7  = sr[7]  * sr[7]  + si[7]  * si[7];
        float p11 = sr[11] * sr[11] + si[11] * si[11];
        float p13 = sr[13] * sr[13] + si[13] * si[13];
        float p14 = sr[14] * sr[14] + si[14] * si[14];
        float p15 = sr[15] * sr[15] + si[15] * si[15];
        float sc = (p0 - p15) + 0.5f * ((p1 + p2 + p4 + p8) - (p7 + p11 + p13 + p14));
        ex = __expf(sc);
        escore[inv[e]] = ex;
    }
    float wsum = ex;
#pragma unroll
    for (int d = 32; d; d >>= 1) wsum += __shfl_xor(wsum, d, 64);
    if ((threadIdx.x & 63) == 0) red[threadIdx.x >> 6] = wsum;
    __syncthreads();
    if (threadIdx.x == 0) atomicAdd(sumexp, red[0] + red[1] + red[2] + red[3]);
}

// ---------------- dst binning (edge_index is layer-invariant: built once) ----

__global__ void k_hist(const int* __restrict__ ei, int* __restrict__ cnt, int E, int EP) {
    int e = blockIdx.x * blockDim.x + threadIdx.x;
    if (e >= EP) return;
    int d_ = (e < E) ? ei[E + e] : e - E;
    atomicAdd(&cnt[d_], 1);
}

__global__ void k_scan(const int* __restrict__ cnt, int* __restrict__ off,
                       int* __restrict__ cur, int N) {
    __shared__ int tot[1024];
    const int t = threadIdx.x;
    const int chunk = (N + 1023) >> 10;
    const int s0 = t * chunk;
    const int s1 = min(s0 + chunk, N);
    int sum = 0;
    for (int i = s0; i < s1; ++i) sum += cnt[i];
    tot[t] = sum;
    __syncthreads();
    for (int d = 1; d < 1024; d <<= 1) {
        int v = (t >= d) ? tot[t - d] : 0;
        __syncthreads();
        tot[t] += v;
        __syncthreads();
    }
    int run = (t == 0) ? 0 : tot[t - 1];
    for (int i = s0; i < s1; ++i) {
        off[i] = run; cur[i] = run;
        run += cnt[i];
    }
}

// one block per dst: h[dst,:] = relu( invS * sum_slot escore[slot]*xcomb[srcs[slot],:] )
__global__ void k_gather(const float* __restrict__ xcomb, const int* __restrict__ srcs,
                         const float* __restrict__ escore, const int* __restrict__ off,
                         const int* __restrict__ cnt, const float* __restrict__ sumexp,
                         float* __restrict__ h) {
    __shared__ int sS[128];
    __shared__ float wS[128];
    const int b = blockIdx.x;
    const int tid = threadIdx.x;  // 128
    const int start = off[b];
    const int num = cnt[b];
    float acc = 0.f;
    for (int base = 0; base < num; base += 128) {
        int m = min(128, num - base);
        if (tid < m) {
            sS[tid] = srcs[start + base + tid];
            wS[tid] = escore[start + base + tid];
        }
        __syncthreads();
        for (int i = 0; i < m; ++i)
            acc += wS[i] * xcomb[(size_t)sS[i] * 128 + tid];
        __syncthreads();
    }
    const float invS = __builtin_amdgcn_rcpf(sumexp[0]);
    h[(size_t)b * 128 + tid] = fmaxf(acc * invS, 0.f);
}

// fused tail: path_in projection + path circuit + epilogue out = M@z + v.
// 256 threads, 64 nodes/block. Phase 1: thread=(node,i) dot read direct from
// global (h is L2-warm; 4 lanes/node share lines). Phase 2: lanes 0-63 run the
// circuit. Phase 3: coalesced 64x32 epilogue. LDS ~3.6 KB (occupancy-friendly).
__global__ void k_tail(const float* __restrict__ h, const float* __restrict__ piW,
                       const float* __restrict__ pib, const float* __restrict__ RP,
                       const float* __restrict__ M, const float* __restrict__ v,
                       float* __restrict__ out, int N) {
    __shared__ float pqS[64 * 8];
    __shared__ float zS[64 * 4];
    __shared__ float MS[128];
    __shared__ float vS[32];
    const int tid = threadIdx.x;  // 256
    const int base = blockIdx.x * 64;
    if (tid < 128) MS[tid] = M[tid];
    else if (tid < 160) vS[tid - 128] = v[tid - 128];
    // phase 1: one projection dot per thread
    {
        const int nl = tid >> 2, i = tid & 3;
        const int node = base + nl;
        if (node < N) {
            float dot = pib[i];
            const float4* w4 = (const float4*)(piW + i * 128);
            const float4* h4 = (const float4*)(h + (size_t)node * 128);
#pragma unroll 8
            for (int c4 = 0; c4 < 32; ++c4) {
                float4 w = w4[c4];
                float4 hv = h4[c4];
                dot += w.x * hv.x + w.y * hv.y + w.z * hv.z + w.w * hv.w;
            }
            float halfang = fast_tanh(dot) * (0.5f * PI_HALF);
            float s, c; __sincosf(halfang, &s, &c);
            pqS[nl * 8 + i * 2]     = c;
            pqS[nl * 8 + i * 2 + 1] = s;
        }
    }
    __syncthreads();
    // phase 2: path circuit, one node per lane (lanes 0-63). H then RY gives a
    // product state with per-wire vector (r*(c-s), r*(c+s)); real until first Rot.
    if (tid < 64 && base + tid < N) {
        const float r = 0.70710678118654752f;
        float c0 = pqS[tid * 8 + 0], s0 = pqS[tid * 8 + 1];
        float c1 = pqS[tid * 8 + 2], s1 = pqS[tid * 8 + 3];
        float c2 = pqS[tid * 8 + 4], s2 = pqS[tid * 8 + 5];
        float c3 = pqS[tid * 8 + 6], s3 = pqS[tid * 8 + 7];
        float u0 = r * (c0 - s0), w0 = r * (c0 + s0);
        float u1 = r * (c1 - s1), w1 = r * (c1 + s1);
        float u2 = r * (c2 - s2), w2 = r * (c2 + s2);
        float u3 = r * (c3 - s3), w3 = r * (c3 + s3);
        float sr[16], si[16];
        prod_init(sr, u0, w0, u1, w1, u2, w2, u3, w3);
        // layer 0: first Rot on real state
        rot_first<8>(sr, si, RP);
        rot_pre<4>(sr, si, RP + 8);
        rot_pre<2>(sr, si, RP + 16);
        rot_pre<1>(sr, si, RP + 24);
        cnot_g<8, 4>(sr, si); cnot_g<4, 2>(sr, si); cnot_g<2, 1>(sr, si);
        // layers 1,2
#pragma unroll
        for (int l = 1; l < 3; ++l) {
            const float* P = RP + l * 32;
            rot_pre<8>(sr, si, P);
            rot_pre<4>(sr, si, P + 8);
            rot_pre<2>(sr, si, P + 16);
            rot_pre<1>(sr, si, P + 24);
            cnot_g<8, 4>(sr, si); cnot_g<4, 2>(sr, si); cnot_g<2, 1>(sr, si);
        }
        float z[4]; zexp_g(sr, si, z);
        zS[tid * 4 + 0] = z[0]; zS[tid * 4 + 1] = z[1];
        zS[tid * 4 + 2] = z[2]; zS[tid * 4 + 3] = z[3];
    }
    __syncthreads();
    // phase 3: epilogue, 64 nodes x 32 outputs, coalesced
#pragma unroll
    for (int k = 0; k < 8; ++k) {
        int flat = k * 256 + tid;
        int nl = flat >> 5;
        int o = flat & 31;
        int node = base + nl;
        if (node < N) {
            out[(size_t)node * 32 + o] = vS[o]
                + MS[o * 4 + 0] * zS[nl * 4 + 0] + MS[o * 4 + 1] * zS[nl * 4 + 1]
                + MS[o * 4 + 2] * zS[nl * 4 + 2] + MS[o * 4 + 3] * zS[nl * 4 + 3];
        }
    }
}

// ---------------- launch ----------------------------------------------------

extern "C" void kernel_launch(void* const* d_in, const int* in_sizes, int n_in,
                              void* d_out, int out_size, void* d_ws, size_t ws_size,
                              hipStream_t stream) {
    const float* x     = (const float*)d_in[0];
    const float* W_in  = (const float*)d_in[1];
    const float* b_in  = (const float*)d_in[2];
    const float* linW  = (const float*)d_in[3];
    const float* linb  = (const float*)d_in[4];
    const float* qpW   = (const float*)d_in[5];
    const float* qpb   = (const float*)d_in[6];
    const float* entp  = (const float*)d_in[7];
    const float* aqW   = (const float*)d_in[8];
    const float* aqb   = (const float*)d_in[9];
    const float* akW   = (const float*)d_in[10];
    const float* akb   = (const float*)d_in[11];
    const float* attqp = (const float*)d_in[12];
    const float* pparm = (const float*)d_in[13];
    const float* piW   = (const float*)d_in[14];
    const float* pib   = (const float*)d_in[15];
    const float* poW   = (const float*)d_in[16];
    const float* pob   = (const float*)d_in[17];
    const float* outW  = (const float*)d_in[18];
    const float* outb  = (const float*)d_in[19];
    const int*   ei    = (const int*)d_in[20];

    const int N  = in_sizes[0] / 64;   // 20000
    const int E  = in_sizes[20] / 2;   // 300000
    const int EP = E + N;              // self-loops appended

    float* ws     = (float*)d_ws;
    float* h      = ws;
    float* xcomb  = h      + (size_t)N * 128;
    float* qbuf   = xcomb  + (size_t)N * 128;
    float* kbuf   = qbuf   + (size_t)N * 8;
    float* escore = kbuf   + (size_t)N * 8;
    float* rotbuf = escore + EP;
    float* Mm     = rotbuf + 36 * 8;
    float* vv     = Mm + 128;
    int*   cnt    = (int*)(vv + 32);
    float* sumexp = (float*)(cnt + N);   // 2 slots (one per layer), zeroed with cnt
    int*   off    = (int*)(sumexp + 4);
    int*   cur    = off + N;
    int*   srcs   = cur + N;
    int*   inv    = srcs + EP;

    const float* rotE = rotbuf;          // 16 matrices
    const float* rotA = rotbuf + 128;    // 8 matrices
    const float* rotP = rotbuf + 192;    // 12 matrices

    const int nb16 = (N + 15) / 16;
    const int nb32 = (N + 31) / 32;
    const int ebl  = (EP + 255) / 256;

    hipMemsetAsync(cnt, 0, (size_t)(N + 4) * sizeof(int), stream);
    k_hist<<<ebl, 256, 0, stream>>>(ei, cnt, E, EP);
    k_scan<<<1, 1024, 0, stream>>>(cnt, off, cur, N);
    k_fsi<<<ebl + 1 + nb32, 256, 0, stream>>>(ei, cur, srcs, inv, E, EP,
                                              entp, attqp, pparm, outW, outb, poW, pob,
                                              rotbuf, Mm, vv, x, W_in, b_in, h, N, ebl);

    for (int l = 0; l < 2; ++l) {
        k_entlin<<<nb16, 128, 0, stream>>>(h, rotE + l * 64,
            linW + (size_t)l * 128 * 128, linb + l * 128,
            qpW + (size_t)l * 128 * 4, qpb + l * 128,
            aqW + (size_t)l * 4 * 128, aqb + l * 4,
            akW + (size_t)l * 4 * 128, akb + l * 4,
            xcomb, qbuf, kbuf, N);
        k_att<<<ebl, 256, 0, stream>>>(qbuf, kbuf, ei, rotA + l * 32, inv,
                                       escore, sumexp + l, E, EP);
        k_gather<<<N, 128, 0, stream>>>(xcomb, srcs, escore, off, cnt, sumexp + l, h);
    }

    k_tail<<<(N + 63) / 64, 256, 0, stream>>>(h, piW, pib, rotP, Mm, vv, (float*)d_out, N);
}

// Round 3
// 355.486 us; speedup vs baseline: 1.1696x; 1.0729x over previous
//
#include <hip/hip_runtime.h>
#include <math.h>

#define PI_HALF 1.57079632679489662f

__device__ __forceinline__ float fast_tanh(float x) {
    float e = __expf(2.f * x);
    return 1.f - 2.f * __builtin_amdgcn_rcpf(e + 1.f);
}

// ---------------- 4-qubit state helpers (compile-time masks -> registers) ----
// wire w (0..3) maps to amplitude-index bit (3-w), i.e. mask = 8 >> w.

// state after per-wire RY layer on |0000>: amp = tensor product of (c,s) per wire.
__device__ __forceinline__ void prod_init(float sr[16],
        float c0, float s0, float c1, float s1,
        float c2, float s2, float c3, float s3) {
    float p2[4];
    p2[0] = c0 * c1; p2[1] = c0 * s1; p2[2] = s0 * c1; p2[3] = s0 * s1;
    float p3[8];
#pragma unroll
    for (int j = 0; j < 4; ++j) { p3[2 * j] = p2[j] * c2; p3[2 * j + 1] = p2[j] * s2; }
#pragma unroll
    for (int j = 0; j < 8; ++j) { sr[2 * j] = p3[j] * c3; sr[2 * j + 1] = p3[j] * s3; }
}

template<int M>
__device__ __forceinline__ void had_r(float sr[16]) {
    const float r = 0.70710678118654752f;
#pragma unroll
    for (int i = 0; i < 16; ++i) {
        if (i & M) continue;
        const int j = i | M;
        float ar = sr[i], br = sr[j];
        sr[i] = (ar + br) * r;
        sr[j] = (ar - br) * r;
    }
}

template<int MC, int MT>
__device__ __forceinline__ void cry_r(float sr[16], float c, float s) {
#pragma unroll
    for (int i = 0; i < 16; ++i) {
        if (!(i & MC) || (i & MT)) continue;
        const int j = i | MT;
        float ar = sr[i], br = sr[j];
        sr[i] = c * ar - s * br;
        sr[j] = s * ar + c * br;
    }
}

template<int MC, int MT>
__device__ __forceinline__ void cnot_r(float sr[16]) {
#pragma unroll
    for (int i = 0; i < 16; ++i) {
        if (!(i & MC) || (i & MT)) continue;
        const int j = i | MT;
        float t = sr[i]; sr[i] = sr[j]; sr[j] = t;
    }
}

template<int MC, int MT>
__device__ __forceinline__ void cnot_g(float sr[16], float si[16]) {
#pragma unroll
    for (int i = 0; i < 16; ++i) {
        if (!(i & MC) || (i & MT)) continue;
        const int j = i | MT;
        float tr = sr[i], ti = si[i];
        sr[i] = sr[j]; si[i] = si[j];
        sr[j] = tr;    si[j] = ti;
    }
}

// full complex Rot gate from precomputed 8-float matrix
template<int M>
__device__ __forceinline__ void rot_pre(float sr[16], float si[16], const float* __restrict__ u) {
    const float u00r = u[0], u00i = u[1], u01r = u[2], u01i = u[3];
    const float u10r = u[4], u10i = u[5], u11r = u[6], u11i = u[7];
#pragma unroll
    for (int i = 0; i < 16; ++i) {
        if (i & M) continue;
        const int j = i | M;
        float ar = sr[i], ai = si[i], br = sr[j], bi = si[j];
        sr[i] = u00r * ar - u00i * ai + u01r * br - u01i * bi;
        si[i] = u00r * ai + u00i * ar + u01r * bi + u01i * br;
        sr[j] = u10r * ar - u10i * ai + u11r * br - u11i * bi;
        si[j] = u10r * ai + u10i * ar + u11r * bi + u11i * br;
    }
}

// first Rot applied to a purely-real state (si implicitly 0); bitwise-identical
// to rot_pre with ai=bi=0 (dropped terms are exact zeros).
template<int M>
__device__ __forceinline__ void rot_first(float sr[16], float si[16], const float* __restrict__ u) {
    const float u00r = u[0], u00i = u[1], u01r = u[2], u01i = u[3];
    const float u10r = u[4], u10i = u[5], u11r = u[6], u11i = u[7];
#pragma unroll
    for (int i = 0; i < 16; ++i) {
        if (i & M) continue;
        const int j = i | M;
        float ar = sr[i], br = sr[j];
        sr[i] = u00r * ar + u01r * br;
        si[i] = u00i * ar + u01i * br;
        sr[j] = u10r * ar + u11r * br;
        si[j] = u10i * ar + u11i * br;
    }
}

__device__ __forceinline__ void zexp_g(const float sr[16], const float si[16], float z[4]) {
    float p[16];
#pragma unroll
    for (int i = 0; i < 16; ++i) p[i] = sr[i] * sr[i] + si[i] * si[i];
    z[0] = z[1] = z[2] = z[3] = 0.f;
#pragma unroll
    for (int i = 0; i < 16; ++i) {
        z[0] += (i & 8) ? -p[i] : p[i];
        z[1] += (i & 4) ? -p[i] : p[i];
        z[2] += (i & 2) ? -p[i] : p[i];
        z[3] += (i & 1) ? -p[i] : p[i];
    }
}

// ---------------- kernels ---------------------------------------------------

// h = relu(x @ W_in^T + b_in) fused with k_fill + k_setup.
// Block roles: [0, eblocks) fill; eblocks: setup; (eblocks, ...] input GEMM (32 nodes/block).
__global__ void k_fsi(const int* __restrict__ ei, int* __restrict__ cur,
                      int* __restrict__ srcs, int* __restrict__ inv, int E, int EP,
                      const float* __restrict__ entp, const float* __restrict__ attqp,
                      const float* __restrict__ pparm,
                      const float* __restrict__ outW, const float* __restrict__ outb,
                      const float* __restrict__ poW, const float* __restrict__ pob,
                      float* __restrict__ rotbuf, float* __restrict__ M,
                      float* __restrict__ v,
                      const float* __restrict__ x, const float* __restrict__ W,
                      const float* __restrict__ b, float* __restrict__ h,
                      int N, int eblocks) {
    __shared__ float xs[32 * 64];
    const int bb = blockIdx.x;
    const int tid = threadIdx.x;  // 256
    if (bb < eblocks) {
        // -------- fill role (counting-sort scatter) --------
        int e = bb * 256 + tid;
        if (e < EP) {
            int s_, d_;
            if (e < E) { s_ = ei[e]; d_ = ei[E + e]; } else { s_ = d_ = e - E; }
            int pos = atomicAdd(&cur[d_], 1);
            srcs[pos] = s_;
            inv[e] = pos;
        }
        return;
    }
    if (bb == eblocks) {
        // -------- setup role: rot matrices + fused output matrix --------
        const int t = tid;
        if (t < 36) {
            const float* p;
            if (t < 16)      p = entp  + t * 3;
            else if (t < 24) p = attqp + (t - 16) * 3;
            else             p = pparm + (t - 24) * 3;
            float phi = p[0], theta = p[1], omega = p[2];
            float st, ct; sincosf(0.5f * theta, &st, &ct);
            float sp, cp; sincosf(0.5f * (phi + omega), &sp, &cp);
            float sm, cm; sincosf(0.5f * (phi - omega), &sm, &cm);
            float* u = rotbuf + t * 8;
            u[0] =  ct * cp;  u[1] = -ct * sp;
            u[2] = -st * cm;  u[3] = -st * sm;
            u[4] =  st * cm;  u[5] = -st * sm;
            u[6] =  ct * cp;  u[7] =  ct * sp;
        } else if (t >= 64 && t < 192) {
            int t2 = t - 64;
            int o = t2 >> 2, i = t2 & 3;
            float acc = 0.f;
            for (int j = 0; j < 128; ++j) acc += outW[o * 128 + j] * poW[j * 4 + i];
            M[t2] = acc;
        } else if (t >= 192 && t < 224) {
            int o = t - 192;
            float acc = outb[o];
            for (int j = 0; j < 128; ++j) acc += outW[o * 128 + j] * pob[j];
            v[o] = acc;
        }
        return;
    }
    // -------- input-GEMM role: 32 nodes per block, thread = (half, channel) --------
    const int base = (bb - eblocks - 1) * 32;
    for (int idx = tid; idx < 32 * 64; idx += 256) {
        int n = base + (idx >> 6);
        xs[idx] = (n < N) ? x[(size_t)n * 64 + (idx & 63)] : 0.f;
    }
    __syncthreads();
    const int ch = tid & 127;
    const int half = tid >> 7;
    float acc[16];
#pragma unroll
    for (int n = 0; n < 16; ++n) acc[n] = 0.f;
    const float4* wr4 = (const float4*)(W + ch * 64);
    for (int c4 = 0; c4 < 16; ++c4) {
        float4 w = wr4[c4];
#pragma unroll
        for (int n = 0; n < 16; ++n) {
            float4 hv = *(const float4*)&xs[(half * 16 + n) * 64 + c4 * 4];
            acc[n] += w.x * hv.x + w.y * hv.y + w.z * hv.z + w.w * hv.w;
        }
    }
    const float bbv = b[ch];
#pragma unroll
    for (int n = 0; n < 16; ++n) {
        int node = base + half * 16 + n;
        if (node < N) h[(size_t)node * 128 + ch] = fmaxf(acc[n] + bbv, 0.f);
    }
}

// entangle circuit + per-node linear/x_comb/q/k kernel.
// 128 threads (2 waves), 16 nodes/block, hs padded to stride 132.
// Middle phase: wave0 does the 128 q/k dots (2/lane), wave1 lanes 0-15 run the
// 16 entangle circuits concurrently. Main GEMM: 2 channels/thread (lane, lane+64)
// so each ds_read_b128 of hs feeds two accumulator sets (halves LDS issue count).
#define HS_STRIDE 132
__global__ void k_entlin(const float* __restrict__ h, const float* __restrict__ rotE2,
                         const float* __restrict__ linW, const float* __restrict__ linb,
                         const float* __restrict__ qpW, const float* __restrict__ qpb,
                         const float* __restrict__ aqW, const float* __restrict__ aqb,
                         const float* __restrict__ akW, const float* __restrict__ akb,
                         float* __restrict__ xcomb, float* __restrict__ qbuf,
                         float* __restrict__ kbuf, int N) {
    __shared__ float hs[16 * HS_STRIDE];
    __shared__ float xqs[16 * 4];
    const int base = blockIdx.x * 16;
    const int tid = threadIdx.x;  // 128
    // stage h tile (float4, padded rows keep 16B alignment: 132*4 % 16 == 0)
    for (int idx = tid; idx < 16 * 32; idx += 128) {
        int n = idx >> 5, c4 = idx & 31;
        int node = base + n;
        float4 hv = (node < N) ? *(const float4*)&h[(size_t)node * 128 + c4 * 4]
                               : make_float4(0.f, 0.f, 0.f, 0.f);
        *(float4*)&hs[n * HS_STRIDE + c4 * 4] = hv;
    }
    __syncthreads();
    if (tid < 64) {
        // wave 0: q/k dots. 128 dots = (node 0..15) x (which 0..7); 2 per lane.
#pragma unroll
        for (int rep = 0; rep < 2; ++rep) {
            const int dt = tid + rep * 64;
            const int nl = dt >> 3;
            const int which = dt & 7;
            const int qi = which & 3;
            const float4* Wp4 = (const float4*)(((which < 4) ? aqW : akW) + qi * 128);
            float dot = (which < 4) ? aqb[qi] : akb[qi];
            for (int c4 = 0; c4 < 32; ++c4) {
                float4 w = Wp4[c4];
                float4 hv = *(const float4*)&hs[nl * HS_STRIDE + c4 * 4];
                dot += w.x * hv.x + w.y * hv.y + w.z * hv.z + w.w * hv.w;
            }
            int node = base + nl;
            if (node < N) {
                float halfang = fast_tanh(dot) * (0.5f * PI_HALF);
                float s, c; __sincosf(halfang, &s, &c);
                float* dst = ((which < 4) ? qbuf : kbuf) + (size_t)node * 8 + qi * 2;
                dst[0] = c; dst[1] = s;
            }
        }
    } else if (tid < 80) {
        // wave 1 lanes 0-15: entangle circuit for node base+(tid-64).
        const int nl = tid - 64;
        if (base + nl < N) {
            float4 hv = *(const float4*)&hs[nl * HS_STRIDE];
            float c0, s0, c1, s1, c2, s2, c3, s3;
            { float a = fast_tanh(hv.x) * (0.5f * PI_HALF); __sincosf(a, &s0, &c0); }
            { float a = fast_tanh(hv.y) * (0.5f * PI_HALF); __sincosf(a, &s1, &c1); }
            { float a = fast_tanh(hv.z) * (0.5f * PI_HALF); __sincosf(a, &s2, &c2); }
            { float a = fast_tanh(hv.w) * (0.5f * PI_HALF); __sincosf(a, &s3, &c3); }
            float sr[16], si[16];
            prod_init(sr, c0, s0, c1, s1, c2, s2, c3, s3);
            // sublayer 0: CNOTs real, first Rot real->complex
            cnot_r<8, 4>(sr); cnot_r<4, 2>(sr); cnot_r<2, 1>(sr);
            rot_first<8>(sr, si, rotE2);
            rot_pre<4>(sr, si, rotE2 + 8);
            rot_pre<2>(sr, si, rotE2 + 16);
            rot_pre<1>(sr, si, rotE2 + 24);
            cnot_g<8, 1>(sr, si);
            // sublayer 1: complex
            cnot_g<8, 4>(sr, si); cnot_g<4, 2>(sr, si); cnot_g<2, 1>(sr, si);
            const float* P = rotE2 + 32;
            rot_pre<8>(sr, si, P);
            rot_pre<4>(sr, si, P + 8);
            rot_pre<2>(sr, si, P + 16);
            rot_pre<1>(sr, si, P + 24);
            cnot_g<8, 1>(sr, si);
            float z[4]; zexp_g(sr, si, z);
            xqs[nl * 4 + 0] = z[0]; xqs[nl * 4 + 1] = z[1];
            xqs[nl * 4 + 2] = z[2]; xqs[nl * 4 + 3] = z[3];
        }
    }
    __syncthreads();
    // main GEMM: wave nh handles nodes nh*8..nh*8+7; lane handles ch=lane, lane+64.
    const int lane = tid & 63;
    const int nh = tid >> 6;
    const int ch0 = lane, ch1 = lane + 64;
    float acc0[8], acc1[8];
#pragma unroll
    for (int n = 0; n < 8; ++n) { acc0[n] = 0.f; acc1[n] = 0.f; }
    const float4* w04 = (const float4*)(linW + ch0 * 128);
    const float4* w14 = (const float4*)(linW + ch1 * 128);
    for (int c4 = 0; c4 < 32; ++c4) {
        float4 wa = w04[c4];
        float4 wb = w14[c4];
#pragma unroll
        for (int n = 0; n < 8; ++n) {
            float4 hv = *(const float4*)&hs[(nh * 8 + n) * HS_STRIDE + c4 * 4];
            acc0[n] += wa.x * hv.x + wa.y * hv.y + wa.z * hv.z + wa.w * hv.w;
            acc1[n] += wb.x * hv.x + wb.y * hv.y + wb.z * hv.z + wb.w * hv.w;
        }
    }
    const float b0 = linb[ch0] + qpb[ch0];
    const float b1 = linb[ch1] + qpb[ch1];
    const float q00 = qpW[ch0 * 4 + 0], q01 = qpW[ch0 * 4 + 1];
    const float q02 = qpW[ch0 * 4 + 2], q03 = qpW[ch0 * 4 + 3];
    const float q10 = qpW[ch1 * 4 + 0], q11 = qpW[ch1 * 4 + 1];
    const float q12 = qpW[ch1 * 4 + 2], q13 = qpW[ch1 * 4 + 3];
#pragma unroll
    for (int n = 0; n < 8; ++n) {
        const int nl = nh * 8 + n;
        const int node = base + nl;
        if (node < N) {
            float x0 = xqs[nl * 4 + 0], x1 = xqs[nl * 4 + 1];
            float x2 = xqs[nl * 4 + 2], x3 = xqs[nl * 4 + 3];
            xcomb[(size_t)node * 128 + ch0] = acc0[n] + b0
                + q00 * x0 + q01 * x1 + q02 * x2 + q03 * x3;
            xcomb[(size_t)node * 128 + ch1] = acc1[n] + b1
                + q10 * x0 + q11 * x1 + q12 * x2 + q13 * x3;
        }
    }
}

// attention circuit per edge. State is purely real through RY+H+CRY (all real
// gates); only the final Rot layer is complex. Score computed directly via
// popcount weights: mean_w z_w = sum_i p_i * (1 - popc(i)/2); 6 terms vanish.
__global__ void k_att(const float* __restrict__ qb, const float* __restrict__ kb,
                      const int* __restrict__ ei, const float* __restrict__ RA,
                      const int* __restrict__ inv, float* __restrict__ escore,
                      float* __restrict__ sumexp, int E, int EP) {
    __shared__ float red[4];
    int e = blockIdx.x * blockDim.x + threadIdx.x;
    float ex = 0.f;
    if (e < EP) {
        int s_, d_;
        if (e < E) { s_ = ei[e]; d_ = ei[E + e]; } else { s_ = d_ = e - E; }
        float4 qa = *(const float4*)&qb[(size_t)s_ * 8];
        float4 qc = *(const float4*)&qb[(size_t)s_ * 8 + 4];
        float4 ka = *(const float4*)&kb[(size_t)d_ * 8];
        float4 kc = *(const float4*)&kb[(size_t)d_ * 8 + 4];
        float sr[16], si[16];
        prod_init(sr, qa.x, qa.y, qa.z, qa.w, qc.x, qc.y, qc.z, qc.w);
        had_r<8>(sr); had_r<4>(sr); had_r<2>(sr); had_r<1>(sr);
        cry_r<8, 4>(sr, ka.x, ka.y);
        cry_r<4, 2>(sr, ka.z, ka.w);
        cry_r<2, 1>(sr, kc.x, kc.y);
        cry_r<1, 8>(sr, kc.z, kc.w);
        rot_first<8>(sr, si, RA);
        rot_pre<4>(sr, si, RA + 8);
        rot_pre<2>(sr, si, RA + 16);
        rot_pre<1>(sr, si, RA + 24);
        float p0  = sr[0]  * sr[0]  + si[0]  * si[0];
        float p1  = sr[1]  * sr[1]  + si[1]  * si[1];
        float p2  = sr[2]  * sr[2]  + si[2]  * si[2];
        float p4  = sr[4]  * sr[4]  + si[4]  * si[4];
        float p8  = sr[8]  * sr[8]  + si[8]  * si[8];
        float p7  = sr[7]  * sr[7]  + si[7]  * si[7];
        float p11 = sr[11] * sr[11] + si[11] * si[11];
        float p13 = sr[13] * sr[13] + si[13] * si[13];
        float p14 = sr[14] * sr[14] + si[14] * si[14];
        float p15 = sr[15] * sr[15] + si[15] * si[15];
        float sc = (p0 - p15) + 0.5f * ((p1 + p2 + p4 + p8) - (p7 + p11 + p13 + p14));
        ex = __expf(sc);
        escore[inv[e]] = ex;
    }
    float wsum = ex;
#pragma unroll
    for (int d = 32; d; d >>= 1) wsum += __shfl_xor(wsum, d, 64);
    if ((threadIdx.x & 63) == 0) red[threadIdx.x >> 6] = wsum;
    __syncthreads();
    if (threadIdx.x == 0) atomicAdd(sumexp, red[0] + red[1] + red[2] + red[3]);
}

// ---------------- dst binning (edge_index is layer-invariant: built once) ----

__global__ void k_hist(const int* __restrict__ ei, int* __restrict__ cnt, int E, int EP) {
    int e = blockIdx.x * blockDim.x + threadIdx.x;
    if (e >= EP) return;
    int d_ = (e < E) ? ei[E + e] : e - E;
    atomicAdd(&cnt[d_], 1);
}

__global__ void k_scan(const int* __restrict__ cnt, int* __restrict__ off,
                       int* __restrict__ cur, int N) {
    __shared__ int tot[1024];
    const int t = threadIdx.x;
    const int chunk = (N + 1023) >> 10;
    const int s0 = t * chunk;
    const int s1 = min(s0 + chunk, N);
    int sum = 0;
    for (int i = s0; i < s1; ++i) sum += cnt[i];
    tot[t] = sum;
    __syncthreads();
    for (int d = 1; d < 1024; d <<= 1) {
        int v = (t >= d) ? tot[t - d] : 0;
        __syncthreads();
        tot[t] += v;
        __syncthreads();
    }
    int run = (t == 0) ? 0 : tot[t - 1];
    for (int i = s0; i < s1; ++i) {
        off[i] = run; cur[i] = run;
        run += cnt[i];
    }
}

// one block per dst: h[dst,:] = relu( invS * sum_slot escore[slot]*xcomb[srcs[slot],:] )
__global__ void k_gather(const float* __restrict__ xcomb, const int* __restrict__ srcs,
                         const float* __restrict__ escore, const int* __restrict__ off,
                         const int* __restrict__ cnt, const float* __restrict__ sumexp,
                         float* __restrict__ h) {
    __shared__ int sS[128];
    __shared__ float wS[128];
    const int b = blockIdx.x;
    const int tid = threadIdx.x;  // 128
    const int start = off[b];
    const int num = cnt[b];
    float acc = 0.f;
    for (int base = 0; base < num; base += 128) {
        int m = min(128, num - base);
        if (tid < m) {
            sS[tid] = srcs[start + base + tid];
            wS[tid] = escore[start + base + tid];
        }
        __syncthreads();
        for (int i = 0; i < m; ++i)
            acc += wS[i] * xcomb[(size_t)sS[i] * 128 + tid];
        __syncthreads();
    }
    const float invS = __builtin_amdgcn_rcpf(sumexp[0]);
    h[(size_t)b * 128 + tid] = fmaxf(acc * invS, 0.f);
}

// fused tail: path_in projection + path circuit + epilogue out = M@z + v.
// 256 threads, 64 nodes/block. Phase 1: thread=(node,i) dot read direct from
// global (h is L2-warm; 4 lanes/node share lines). Phase 2: lanes 0-63 run the
// circuit. Phase 3: coalesced 64x32 epilogue. LDS ~3.6 KB (occupancy-friendly).
__global__ void k_tail(const float* __restrict__ h, const float* __restrict__ piW,
                       const float* __restrict__ pib, const float* __restrict__ RP,
                       const float* __restrict__ M, const float* __restrict__ v,
                       float* __restrict__ out, int N) {
    __shared__ float pqS[64 * 8];
    __shared__ float zS[64 * 4];
    __shared__ float MS[128];
    __shared__ float vS[32];
    const int tid = threadIdx.x;  // 256
    const int base = blockIdx.x * 64;
    if (tid < 128) MS[tid] = M[tid];
    else if (tid < 160) vS[tid - 128] = v[tid - 128];
    // phase 1: one projection dot per thread
    {
        const int nl = tid >> 2, i = tid & 3;
        const int node = base + nl;
        if (node < N) {
            float dot = pib[i];
            const float4* w4 = (const float4*)(piW + i * 128);
            const float4* h4 = (const float4*)(h + (size_t)node * 128);
#pragma unroll 8
            for (int c4 = 0; c4 < 32; ++c4) {
                float4 w = w4[c4];
                float4 hv = h4[c4];
                dot += w.x * hv.x + w.y * hv.y + w.z * hv.z + w.w * hv.w;
            }
            float halfang = fast_tanh(dot) * (0.5f * PI_HALF);
            float s, c; __sincosf(halfang, &s, &c);
            pqS[nl * 8 + i * 2]     = c;
            pqS[nl * 8 + i * 2 + 1] = s;
        }
    }
    __syncthreads();
    // phase 2: path circuit, one node per lane (lanes 0-63). H then RY gives a
    // product state with per-wire vector (r*(c-s), r*(c+s)); real until first Rot.
    if (tid < 64 && base + tid < N) {
        const float r = 0.70710678118654752f;
        float c0 = pqS[tid * 8 + 0], s0 = pqS[tid * 8 + 1];
        float c1 = pqS[tid * 8 + 2], s1 = pqS[tid * 8 + 3];
        float c2 = pqS[tid * 8 + 4], s2 = pqS[tid * 8 + 5];
        float c3 = pqS[tid * 8 + 6], s3 = pqS[tid * 8 + 7];
        float u0 = r * (c0 - s0), w0 = r * (c0 + s0);
        float u1 = r * (c1 - s1), w1 = r * (c1 + s1);
        float u2 = r * (c2 - s2), w2 = r * (c2 + s2);
        float u3 = r * (c3 - s3), w3 = r * (c3 + s3);
        float sr[16], si[16];
        prod_init(sr, u0, w0, u1, w1, u2, w2, u3, w3);
        // layer 0: first Rot on real state
        rot_first<8>(sr, si, RP);
        rot_pre<4>(sr, si, RP + 8);
        rot_pre<2>(sr, si, RP + 16);
        rot_pre<1>(sr, si, RP + 24);
        cnot_g<8, 4>(sr, si); cnot_g<4, 2>(sr, si); cnot_g<2, 1>(sr, si);
        // layers 1,2
#pragma unroll
        for (int l = 1; l < 3; ++l) {
            const float* P = RP + l * 32;
            rot_pre<8>(sr, si, P);
            rot_pre<4>(sr, si, P + 8);
            rot_pre<2>(sr, si, P + 16);
            rot_pre<1>(sr, si, P + 24);
            cnot_g<8, 4>(sr, si); cnot_g<4, 2>(sr, si); cnot_g<2, 1>(sr, si);
        }
        float z[4]; zexp_g(sr, si, z);
        zS[tid * 4 + 0] = z[0]; zS[tid * 4 + 1] = z[1];
        zS[tid * 4 + 2] = z[2]; zS[tid * 4 + 3] = z[3];
    }
    __syncthreads();
    // phase 3: epilogue, 64 nodes x 32 outputs, coalesced
#pragma unroll
    for (int k = 0; k < 8; ++k) {
        int flat = k * 256 + tid;
        int nl = flat >> 5;
        int o = flat & 31;
        int node = base + nl;
        if (node < N) {
            out[(size_t)node * 32 + o] = vS[o]
                + MS[o * 4 + 0] * zS[nl * 4 + 0] + MS[o * 4 + 1] * zS[nl * 4 + 1]
                + MS[o * 4 + 2] * zS[nl * 4 + 2] + MS[o * 4 + 3] * zS[nl * 4 + 3];
        }
    }
}

// ---------------- launch ----------------------------------------------------

extern "C" void kernel_launch(void* const* d_in, const int* in_sizes, int n_in,
                              void* d_out, int out_size, void* d_ws, size_t ws_size,
                              hipStream_t stream) {
    const float* x     = (const float*)d_in[0];
    const float* W_in  = (const float*)d_in[1];
    const float* b_in  = (const float*)d_in[2];
    const float* linW  = (const float*)d_in[3];
    const float* linb  = (const float*)d_in[4];
    const float* qpW   = (const float*)d_in[5];
    const float* qpb   = (const float*)d_in[6];
    const float* entp  = (const float*)d_in[7];
    const float* aqW   = (const float*)d_in[8];
    const float* aqb   = (const float*)d_in[9];
    const float* akW   = (const float*)d_in[10];
    const float* akb   = (const float*)d_in[11];
    const float* attqp = (const float*)d_in[12];
    const float* pparm = (const float*)d_in[13];
    const float* piW   = (const float*)d_in[14];
    const float* pib   = (const float*)d_in[15];
    const float* poW   = (const float*)d_in[16];
    const float* pob   = (const float*)d_in[17];
    const float* outW  = (const float*)d_in[18];
    const float* outb  = (const float*)d_in[19];
    const int*   ei    = (const int*)d_in[20];

    const int N  = in_sizes[0] / 64;   // 20000
    const int E  = in_sizes[20] / 2;   // 300000
    const int EP = E + N;              // self-loops appended

    float* ws     = (float*)d_ws;
    float* h      = ws;
    float* xcomb  = h      + (size_t)N * 128;
    float* qbuf   = xcomb  + (size_t)N * 128;
    float* kbuf   = qbuf   + (size_t)N * 8;
    float* escore = kbuf   + (size_t)N * 8;
    float* rotbuf = escore + EP;
    float* Mm     = rotbuf + 36 * 8;
    float* vv     = Mm + 128;
    int*   cnt    = (int*)(vv + 32);
    float* sumexp = (float*)(cnt + N);   // 2 slots (one per layer), zeroed with cnt
    int*   off    = (int*)(sumexp + 4);
    int*   cur    = off + N;
    int*   srcs   = cur + N;
    int*   inv    = srcs + EP;

    const float* rotE = rotbuf;          // 16 matrices
    const float* rotA = rotbuf + 128;    // 8 matrices
    const float* rotP = rotbuf + 192;    // 12 matrices

    const int nb16 = (N + 15) / 16;
    const int nb32 = (N + 31) / 32;
    const int ebl  = (EP + 255) / 256;

    hipMemsetAsync(cnt, 0, (size_t)(N + 4) * sizeof(int), stream);
    k_hist<<<ebl, 256, 0, stream>>>(ei, cnt, E, EP);
    k_scan<<<1, 1024, 0, stream>>>(cnt, off, cur, N);
    k_fsi<<<ebl + 1 + nb32, 256, 0, stream>>>(ei, cur, srcs, inv, E, EP,
                                              entp, attqp, pparm, outW, outb, poW, pob,
                                              rotbuf, Mm, vv, x, W_in, b_in, h, N, ebl);

    for (int l = 0; l < 2; ++l) {
        k_entlin<<<nb16, 128, 0, stream>>>(h, rotE + l * 64,
            linW + (size_t)l * 128 * 128, linb + l * 128,
            qpW + (size_t)l * 128 * 4, qpb + l * 128,
            aqW + (size_t)l * 4 * 128, aqb + l * 4,
            akW + (size_t)l * 4 * 128, akb + l * 4,
            xcomb, qbuf, kbuf, N);
        k_att<<<ebl, 256, 0, stream>>>(qbuf, kbuf, ei, rotA + l * 32, inv,
                                       escore, sumexp + l, E, EP);
        k_gather<<<N, 128, 0, stream>>>(xcomb, srcs, escore, off, cnt, sumexp + l, h);
    }

    k_tail<<<(N + 63) / 64, 256, 0, stream>>>(h, piW, pib, rotP, Mm, vv, (float*)d_out, N);
}